// Round 6
// baseline (1052.052 us; speedup 1.0000x reference)
//
#include <hip/hip_runtime.h>
#include <math.h>

// Squeeze-Excitation, single-HBM-read persistent kernel, double-buffered LDS.
// 256 blocks (1/CU, cooperative) x 512 thr. chunk = batch (32), block = channel.
// Per chunk: reduce buf[cur] -> publish mean -> ISSUE next DMA (buf[cur^1])
// -> spin on per-batch counter (DMA flies underneath) -> wave0-only MLP ->
// scale+store -> vmcnt(8) retires exactly this wave's 8 DMA ops (in-order),
// stores keep flying. Each wave reduces only LDS its own DMA wrote.

#define CH   256
#define CR   16
#define NBLK 256
#define NTHR 512
#define NB   32      // chunks == batches
#define PL4  4096    // f32x4 per plane
#define KPT  8       // DMA / store ops per thread (1 plane / 512 thr)

typedef float f32x4 __attribute__((ext_vector_type(4)));
#define AS1 __attribute__((address_space(1)))
#define AS3 __attribute__((address_space(3)))

__global__ __launch_bounds__(NTHR, 1) void se_fused(
    const float* __restrict__ x,
    const float* __restrict__ w1,
    const float* __restrict__ w2,
    float* __restrict__ out,
    float* __restrict__ y,
    unsigned* __restrict__ ready)
{
    const int bid  = blockIdx.x;           // channel this block owns
    const int t    = threadIdx.x;
    const int lane = t & 63, wid = t >> 6;

    __shared__ f32x4 buf[2][PL4];          // 2 x 64 KiB
    __shared__ float w1s[CR * CH];         // 16 KiB
    __shared__ float yrow[CH];
    __shared__ float red[8];
    __shared__ float s_sh;

    // per-lane w2 element for the MLP contraction (j = lane>>2)
    const float w2v = w2[bid * CR + (lane >> 2)];

    // ---- prologue: DMA chunk 0, stage w1 ----
    {
        const AS1 f32x4* g4 = (const AS1 f32x4*)x + (size_t)bid * PL4;
#pragma unroll
        for (int k = 0; k < KPT; ++k)
            __builtin_amdgcn_global_load_lds(
                (const AS1 void*)(g4 + k * NTHR + t),
                (AS3 void*)(&buf[0][k * NTHR + (wid << 6)]), 16, 0, 0);
    }
    for (int i = t; i < CR * CH; i += NTHR) w1s[i] = w1[i];
    asm volatile("s_waitcnt vmcnt(0)" ::: "memory");
    __syncthreads();

    for (int ck = 0; ck < NB; ++ck) {
        const int cur = ck & 1;

        // ---- plane sum from LDS (each wave reads what its DMA wrote) ----
        float sum = 0.f;
#pragma unroll
        for (int k = 0; k < KPT; ++k) {
            f32x4 v = buf[cur][k * NTHR + t];
            sum += (v.x + v.y) + (v.z + v.w);
        }
#pragma unroll
        for (int off = 32; off; off >>= 1)
            sum += __shfl_down(sum, off, 64);
        if (lane == 0) red[wid] = sum;
        __syncthreads();

        // ---- publish mean + arrive (t0); release orders y before counter --
        if (t == 0) {
            float tot = 0.f;
#pragma unroll
            for (int w = 0; w < 8; ++w) tot += red[w];
            __hip_atomic_store(&y[(size_t)ck * CH + bid],
                               tot * (1.f / 16384.f),
                               __ATOMIC_RELAXED, __HIP_MEMORY_SCOPE_AGENT);
            __hip_atomic_fetch_add(&ready[ck], 1u,
                                   __ATOMIC_RELEASE, __HIP_MEMORY_SCOPE_AGENT);
        }

        // ---- issue next-chunk DMA NOW (flies under spin + MLP) ----
        if (ck + 1 < NB) {
            const AS1 f32x4* g4 =
                (const AS1 f32x4*)x + ((size_t)(ck + 1) * CH + bid) * PL4;
#pragma unroll
            for (int k = 0; k < KPT; ++k)
                __builtin_amdgcn_global_load_lds(
                    (const AS1 void*)(g4 + k * NTHR + t),
                    (AS3 void*)(&buf[cur ^ 1][k * NTHR + (wid << 6)]), 16, 0, 0);
        }

        // ---- wave 0 only: wait batch ready, MLP -> s_sh ----
        if (wid == 0) {
            if (lane == 0) {
                while (__hip_atomic_load(&ready[ck], __ATOMIC_RELAXED,
                                         __HIP_MEMORY_SCOPE_AGENT) < NBLK)
                    __builtin_amdgcn_s_sleep(2);
                // acquire: invalidate caches so plain y loads below are fresh
                (void)__hip_atomic_load(&ready[ck], __ATOMIC_ACQUIRE,
                                        __HIP_MEMORY_SCOPE_AGENT);
            }
            // 4 contiguous channels per lane
            const f32x4* yp = reinterpret_cast<const f32x4*>(y + (size_t)ck * CH);
            f32x4 yv = yp[lane];
            reinterpret_cast<f32x4*>(yrow)[lane] = yv;   // same-wave LDS bounce
            // h_j partial: j = lane>>2 owns channels seg*64..seg*64+63
            const int j = lane >> 2, seg = lane & 3;
            float part = 0.f;
#pragma unroll
            for (int m = 0; m < 64; ++m)
                part += yrow[seg * 64 + m] * w1s[j * CH + seg * 64 + m];
            part += __shfl_down(part, 2, 4);
            part += __shfl_down(part, 1, 4);
            float contrib = (seg == 0) ? fmaxf(part, 0.f) * w2v : 0.f;
#pragma unroll
            for (int off = 32; off; off >>= 1)
                contrib += __shfl_down(contrib, off, 64);
            if (lane == 0) s_sh = 1.f / (1.f + expf(-contrib));
        }
        __syncthreads();

        // ---- scale + store ----
        {
            const float sc = s_sh;
            f32x4* o4 = (f32x4*)out + ((size_t)ck * CH + bid) * PL4;
#pragma unroll
            for (int k = 0; k < KPT; ++k)
                o4[k * NTHR + t] = buf[cur][k * NTHR + t] * sc;
        }

        // retire this wave's 8 DMA ops (oldest); 8 stores keep flying
        asm volatile("s_waitcnt vmcnt(8)" ::: "memory");
        __builtin_amdgcn_s_barrier();
    }
}

extern "C" void kernel_launch(void* const* d_in, const int* in_sizes, int n_in,
                              void* d_out, int out_size, void* d_ws, size_t ws_size,
                              hipStream_t stream) {
    const float* x  = (const float*)d_in[0];
    const float* w1 = (const float*)d_in[1];
    const float* w2 = (const float*)d_in[2];
    float* out = (float*)d_out;

    float*    y     = (float*)d_ws;                                   // 8192 f32
    unsigned* ready = (unsigned*)((char*)d_ws + 8192 * sizeof(float)); // 32 u32

    hipMemsetAsync(ready, 0, 32 * sizeof(unsigned), stream);

    void* args[] = { (void*)&x, (void*)&w1, (void*)&w2, (void*)&out,
                     (void*)&y, (void*)&ready };
    hipLaunchCooperativeKernel((void*)se_fused, dim3(NBLK), dim3(NTHR),
                               args, 0, stream);
}

// Round 7
// 530.007 us; speedup vs baseline: 1.9850x; 1.9850x over previous
//
#include <hip/hip_runtime.h>
#include <math.h>

// Squeeze-Excitation, single-HBM-read persistent kernel, pipelined.
// 256 blocks (1/CU) x 512 thr; block = channel, chunk = batch.
// h=relu(W1 y) is LINEAR in y pre-activation -> each block atomicAdds
// y_c*w1[j,c] into hacc[chunk][j]; readers need only 16 loads + dot.
// Pipeline: iter i = {spin ready[i] (published last iter, ~0 wait) ->
// s=sigmoid(relu(hacc)@w2) -> scale+store chunk i -> DMA chunk i+2 ->
// vmcnt(16) -> reduce chunk i+1 -> publish}. All atomics RELAXED,
// ordering via counted s_waitcnt only (R6's release/acquire emitted
// per-chunk L2 writeback/invalidate = 3x cost).

#define CH   256
#define CR   16
#define NBLK 256
#define NTHR 512
#define NB   32      // chunks == batches
#define PL4  4096    // f32x4 per plane
#define KPT  8       // vmem ops per thread per plane

typedef float f32x4 __attribute__((ext_vector_type(4)));
#define AS1 __attribute__((address_space(1)))
#define AS3 __attribute__((address_space(3)))

__global__ __launch_bounds__(NTHR, 1) void se_fused(
    const float* __restrict__ x,
    const float* __restrict__ w1,
    const float* __restrict__ w2,
    float* __restrict__ out,
    float* __restrict__ hacc,      // [NB][CR] pre-activation accumulators
    unsigned* __restrict__ ready)  // [NB] arrival counters
{
    const int bid  = blockIdx.x;           // channel this block owns
    const int t    = threadIdx.x;
    const int lane = t & 63, wid = t >> 6;

    __shared__ f32x4 buf[2][PL4];          // 2 x 64 KiB double buffer
    __shared__ float red[8];
    __shared__ float s_sh;

    // wave-0 lane j (<16) holds w1[j, bid] and w2[bid, j]
    float w1v = 0.f, w2v = 0.f;
    if (wid == 0 && lane < CR) {
        w1v = w1[lane * CH + bid];
        w2v = w2[bid * CR + lane];
    }

    // ---- prologue: DMA chunks 0 and 1; reduce+publish chunk 0 ----
    {
        const AS1 f32x4* g0 = (const AS1 f32x4*)x + (size_t)bid * PL4;
        const AS1 f32x4* g1 = (const AS1 f32x4*)x + ((size_t)CH + bid) * PL4;
#pragma unroll
        for (int k = 0; k < KPT; ++k)
            __builtin_amdgcn_global_load_lds((const AS1 void*)(g0 + k * NTHR + t),
                (AS3 void*)(&buf[0][k * NTHR + (wid << 6)]), 16, 0, 0);
#pragma unroll
        for (int k = 0; k < KPT; ++k)
            __builtin_amdgcn_global_load_lds((const AS1 void*)(g1 + k * NTHR + t),
                (AS3 void*)(&buf[1][k * NTHR + (wid << 6)]), 16, 0, 0);
    }
    asm volatile("s_waitcnt vmcnt(8)" ::: "memory");   // chunk0 (8 oldest) done
    {
        float sum = 0.f;
#pragma unroll
        for (int k = 0; k < KPT; ++k) {
            f32x4 v = buf[0][k * NTHR + t];
            sum += (v.x + v.y) + (v.z + v.w);
        }
#pragma unroll
        for (int off = 32; off; off >>= 1) sum += __shfl_down(sum, off, 64);
        if (lane == 0) red[wid] = sum;
    }
    __syncthreads();
    if (wid == 0 && lane < CR) {
        float tot = 0.f;
#pragma unroll
        for (int w = 0; w < 8; ++w) tot += red[w];
        const float y = tot * (1.f / 16384.f);
        __hip_atomic_fetch_add(&hacc[lane], y * w1v,
                               __ATOMIC_RELAXED, __HIP_MEMORY_SCOPE_AGENT);
        asm volatile("s_waitcnt vmcnt(0)" ::: "memory");   // adds committed
        if (lane == 0)
            __hip_atomic_fetch_add(&ready[0], 1u,
                                   __ATOMIC_RELAXED, __HIP_MEMORY_SCOPE_AGENT);
    }

    // ---- main pipeline ----
    for (int i = 0; i < NB; ++i) {
        const int cur = i & 1;

        // step0: wave 0 waits chunk i ready (published last iter) -> s_sh
        if (wid == 0) {
            if (lane == 0) {
                while (__hip_atomic_load(&ready[i], __ATOMIC_RELAXED,
                                         __HIP_MEMORY_SCOPE_AGENT) < NBLK)
                    __builtin_amdgcn_s_sleep(1);
            }
            float hv = 0.f;
            if (lane < CR)
                hv = fmaxf(__hip_atomic_load(&hacc[i * CR + lane],
                                             __ATOMIC_RELAXED,
                                             __HIP_MEMORY_SCOPE_AGENT),
                           0.f) * w2v;
            hv += __shfl_down(hv, 8, 16);
            hv += __shfl_down(hv, 4, 16);
            hv += __shfl_down(hv, 2, 16);
            hv += __shfl_down(hv, 1, 16);
            if (lane == 0) s_sh = 1.f / (1.f + expf(-hv));
        }
        __syncthreads();

        // step2: scale + store chunk i; then DMA chunk i+2 into same buffer
        {
            const float sc = s_sh;
            f32x4* o4 = (f32x4*)out + ((size_t)i * CH + bid) * PL4;
#pragma unroll
            for (int k = 0; k < KPT; ++k)
                o4[k * NTHR + t] = buf[cur][k * NTHR + t] * sc;
        }
        asm volatile("s_waitcnt lgkmcnt(0)" ::: "memory");  // ds_reads retired
        if (i + 2 < NB) {
            const AS1 f32x4* g =
                (const AS1 f32x4*)x + ((size_t)(i + 2) * CH + bid) * PL4;
#pragma unroll
            for (int k = 0; k < KPT; ++k)
                __builtin_amdgcn_global_load_lds((const AS1 void*)(g + k * NTHR + t),
                    (AS3 void*)(&buf[cur][k * NTHR + (wid << 6)]), 16, 0, 0);
        }

        // step3: reduce chunk i+1 (its DMA has had a full iter to land)
        if (i + 1 < NB) {
            // newer-than-DMA(i+1): stores(i)=8 [+ DMA(i+2)=8 if issued]
            if (i + 2 < NB) asm volatile("s_waitcnt vmcnt(16)" ::: "memory");
            else            asm volatile("s_waitcnt vmcnt(8)"  ::: "memory");
            float sum = 0.f;
#pragma unroll
            for (int k = 0; k < KPT; ++k) {
                f32x4 v = buf[cur ^ 1][k * NTHR + t];
                sum += (v.x + v.y) + (v.z + v.w);
            }
#pragma unroll
            for (int off = 32; off; off >>= 1) sum += __shfl_down(sum, off, 64);
            if (lane == 0) red[wid] = sum;
            __syncthreads();

            // step4: publish chunk i+1
            if (wid == 0 && lane < CR) {
                float tot = 0.f;
#pragma unroll
                for (int w = 0; w < 8; ++w) tot += red[w];
                const float y = tot * (1.f / 16384.f);
                __hip_atomic_fetch_add(&hacc[(i + 1) * CR + lane], y * w1v,
                                       __ATOMIC_RELAXED, __HIP_MEMORY_SCOPE_AGENT);
                asm volatile("s_waitcnt vmcnt(0)" ::: "memory");
                if (lane == 0)
                    __hip_atomic_fetch_add(&ready[i + 1], 1u,
                                           __ATOMIC_RELAXED, __HIP_MEMORY_SCOPE_AGENT);
            }
        }
    }
}

extern "C" void kernel_launch(void* const* d_in, const int* in_sizes, int n_in,
                              void* d_out, int out_size, void* d_ws, size_t ws_size,
                              hipStream_t stream) {
    const float* x  = (const float*)d_in[0];
    const float* w1 = (const float*)d_in[1];
    const float* w2 = (const float*)d_in[2];
    float* out = (float*)d_out;

    float*    hacc  = (float*)d_ws;                         // NB*CR floats
    unsigned* ready = (unsigned*)((char*)d_ws + NB * CR * sizeof(float));

    // zero hacc + ready (contiguous), captured in the graph each replay
    hipMemsetAsync(d_ws, 0, NB * CR * sizeof(float) + NB * sizeof(unsigned),
                   stream);

    void* args[] = { (void*)&x, (void*)&w1, (void*)&w2, (void*)&out,
                     (void*)&hacc, (void*)&ready };
    hipLaunchCooperativeKernel((void*)se_fused, dim3(NBLK), dim3(NTHR),
                               args, 0, stream);
}

// Round 8
// 384.327 us; speedup vs baseline: 2.7374x; 1.3791x over previous
//
#include <hip/hip_runtime.h>
#include <math.h>

// Squeeze-Excitation, single-HBM-read persistent kernel, RMW-free sync.
// 256 blocks (1/CU) x 512 thr; block = channel, chunk = batch.
// R7 lesson: 256-CU same-address atomicAdd chains cost ~40ns each serialized
// (~10us/chunk). Replace ALL RMWs with: plain relaxed agent stores of y_c
// (256 distinct addresses, parallel) + consumers POLL THE VALUES against a
// NaN sentinel (ws poisoned 0xFF per launch). Pipeline order as R7:
// spin+MLP(i) -> scale+store(i) -> DMA(i+2) -> vmcnt(16) -> reduce(i+1)
// -> publish(i+1). Stores+DMA stay in flight through the sync phase.

#define CH   256
#define CR   16
#define NBLK 256
#define NTHR 512
#define NB   32      // chunks == batches
#define PL4  4096    // f32x4 per plane
#define KPT  8       // vmem ops per thread per plane
#define SENT 0xFFFFFFFFu

typedef float f32x4 __attribute__((ext_vector_type(4)));
#define AS1 __attribute__((address_space(1)))
#define AS3 __attribute__((address_space(3)))

__global__ __launch_bounds__(NTHR, 1) void se_fused(
    const float* __restrict__ x,
    const float* __restrict__ w1,
    const float* __restrict__ w2,
    float* __restrict__ out,
    float* __restrict__ y)        // [NB][CH], poisoned 0xFF each launch
{
    const int bid  = blockIdx.x;          // channel this block owns
    const int t    = threadIdx.x;
    const int lane = t & 63, wid = t >> 6;

    __shared__ f32x4 buf[2][PL4];         // 2 x 64 KiB
    __shared__ float w1s[CR * 260];       // pitch 260 (j*260%32=4j -> 2-way max)
    __shared__ float yq[4 * 68];          // batch means, quarter pitch 68
    __shared__ float red[8];
    __shared__ float s_sh;

    // stage w1 (one-time)
    for (int i = t; i < CR * CH; i += NTHR)
        w1s[(i >> 8) * 260 + (i & 255)] = w1[i];

    // wave-0 MLP lane roles: j = lane>>2 (hidden unit), q = lane&3 (quarter)
    const int jj = lane >> 2, qq = lane & 3;
    float w2v = 0.f;
    if (wid == 0 && qq == 0) w2v = w2[bid * CR + jj];

    // ---- prologue: DMA chunks 0,1; reduce+publish chunk 0 ----
    {
        const AS1 f32x4* g0 = (const AS1 f32x4*)x + (size_t)bid * PL4;
        const AS1 f32x4* g1 = (const AS1 f32x4*)x + ((size_t)CH + bid) * PL4;
#pragma unroll
        for (int k = 0; k < KPT; ++k)
            __builtin_amdgcn_global_load_lds((const AS1 void*)(g0 + k * NTHR + t),
                (AS3 void*)(&buf[0][k * NTHR + (wid << 6)]), 16, 0, 0);
#pragma unroll
        for (int k = 0; k < KPT; ++k)
            __builtin_amdgcn_global_load_lds((const AS1 void*)(g1 + k * NTHR + t),
                (AS3 void*)(&buf[1][k * NTHR + (wid << 6)]), 16, 0, 0);
    }
    asm volatile("s_waitcnt vmcnt(8)" ::: "memory");   // chunk 0 landed
    {
        float sum = 0.f;
#pragma unroll
        for (int k = 0; k < KPT; ++k) {
            f32x4 v = buf[0][k * NTHR + t];
            sum += (v.x + v.y) + (v.z + v.w);
        }
#pragma unroll
        for (int off = 32; off; off >>= 1) sum += __shfl_down(sum, off, 64);
        if (lane == 0) red[wid] = sum;
    }
    __syncthreads();
    if (t == 0) {
        float tot = 0.f;
#pragma unroll
        for (int w = 0; w < 8; ++w) tot += red[w];
        __hip_atomic_store(&y[bid], tot * (1.f / 16384.f),
                           __ATOMIC_RELAXED, __HIP_MEMORY_SCOPE_AGENT);
    }
    __syncthreads();   // w1s staging + red reuse guard

    // ---- main pipeline ----
    for (int i = 0; i < NB; ++i) {
        const int cur = i & 1;

        // step0: wave 0 polls chunk i's 256 y values (sentinel = NaN bits),
        //        then computes the MLP -> s_sh. No RMW anywhere.
        if (wid == 0) {
            const unsigned* yu = (const unsigned*)(y + (size_t)i * CH);
            unsigned u0, u1, u2, u3;
            for (;;) {
                u0 = __hip_atomic_load(&yu[4 * lane + 0], __ATOMIC_RELAXED,
                                       __HIP_MEMORY_SCOPE_AGENT);
                u1 = __hip_atomic_load(&yu[4 * lane + 1], __ATOMIC_RELAXED,
                                       __HIP_MEMORY_SCOPE_AGENT);
                u2 = __hip_atomic_load(&yu[4 * lane + 2], __ATOMIC_RELAXED,
                                       __HIP_MEMORY_SCOPE_AGENT);
                u3 = __hip_atomic_load(&yu[4 * lane + 3], __ATOMIC_RELAXED,
                                       __HIP_MEMORY_SCOPE_AGENT);
                bool ok = (u0 != SENT) & (u1 != SENT) & (u2 != SENT) & (u3 != SENT);
                if (__all(ok)) break;
                __builtin_amdgcn_s_sleep(1);
            }
            // lane l holds channels 4l..4l+3 -> LDS bounce (padded quarters)
            f32x4 yv;
            yv.x = __uint_as_float(u0); yv.y = __uint_as_float(u1);
            yv.z = __uint_as_float(u2); yv.w = __uint_as_float(u3);
            *(f32x4*)&yq[(lane >> 4) * 68 + ((4 * lane) & 63)] = yv;
            // dot: lane(j,q) covers channels q*64..q*64+63 of hidden unit j
            float part = 0.f;
#pragma unroll
            for (int m = 0; m < 16; ++m) {
                f32x4 a = *(const f32x4*)&yq[qq * 68 + 4 * m];
                f32x4 b = *(const f32x4*)&w1s[jj * 260 + qq * 64 + 4 * m];
                part += a.x * b.x + a.y * b.y + a.z * b.z + a.w * b.w;
            }
            part += __shfl_down(part, 2, 64);
            part += __shfl_down(part, 1, 64);
            float contrib = (qq == 0) ? fmaxf(part, 0.f) * w2v : 0.f;
#pragma unroll
            for (int off = 32; off; off >>= 1)
                contrib += __shfl_down(contrib, off, 64);
            if (lane == 0) s_sh = 1.f / (1.f + expf(-contrib));
        }
        __syncthreads();

        // step1: scale + store chunk i (stores stream on the bus)
        {
            const float sc = s_sh;
            f32x4* o4 = (f32x4*)out + ((size_t)i * CH + bid) * PL4;
#pragma unroll
            for (int k = 0; k < KPT; ++k)
                o4[k * NTHR + t] = buf[cur][k * NTHR + t] * sc;
        }

        // step2: per-wave LDS reads retired -> DMA chunk i+2 into same buffer
        asm volatile("s_waitcnt lgkmcnt(0)" ::: "memory");
        if (i + 2 < NB) {
            const AS1 f32x4* g =
                (const AS1 f32x4*)x + ((size_t)(i + 2) * CH + bid) * PL4;
#pragma unroll
            for (int k = 0; k < KPT; ++k)
                __builtin_amdgcn_global_load_lds((const AS1 void*)(g + k * NTHR + t),
                    (AS3 void*)(&buf[cur][k * NTHR + (wid << 6)]), 16, 0, 0);
        }

        // step3: reduce chunk i+1, publish its y (single plain store)
        if (i + 1 < NB) {
            if (i + 2 < NB) asm volatile("s_waitcnt vmcnt(16)" ::: "memory");
            else            asm volatile("s_waitcnt vmcnt(8)"  ::: "memory");
            float sum = 0.f;
#pragma unroll
            for (int k = 0; k < KPT; ++k) {
                f32x4 v = buf[cur ^ 1][k * NTHR + t];
                sum += (v.x + v.y) + (v.z + v.w);
            }
#pragma unroll
            for (int off = 32; off; off >>= 1) sum += __shfl_down(sum, off, 64);
            if (lane == 0) red[wid] = sum;
            __syncthreads();
            if (t == 0) {
                float tot = 0.f;
#pragma unroll
                for (int w = 0; w < 8; ++w) tot += red[w];
                __hip_atomic_store(&y[(size_t)(i + 1) * CH + bid],
                                   tot * (1.f / 16384.f),
                                   __ATOMIC_RELAXED, __HIP_MEMORY_SCOPE_AGENT);
            }
        }
    }
}

extern "C" void kernel_launch(void* const* d_in, const int* in_sizes, int n_in,
                              void* d_out, int out_size, void* d_ws, size_t ws_size,
                              hipStream_t stream) {
    const float* x  = (const float*)d_in[0];
    const float* w1 = (const float*)d_in[1];
    const float* w2 = (const float*)d_in[2];
    float* out = (float*)d_out;
    float* y   = (float*)d_ws;                    // NB*CH floats

    // poison y with NaN sentinel (0xFF bytes) every launch — capture-safe
    hipMemsetAsync(y, 0xFF, NB * CH * sizeof(float), stream);

    void* args[] = { (void*)&x, (void*)&w1, (void*)&w2, (void*)&out, (void*)&y };
    hipLaunchCooperativeKernel((void*)se_fused, dim3(NBLK), dim3(NTHR),
                               args, 0, stream);
}